// Round 1
// baseline (487.102 us; speedup 1.0000x reference)
//
#include <hip/hip_runtime.h>

#define C 32
#define BINS (C * C)
#define FLT_EPS 1.1920928955078125e-07f

// 8 lanes per row, each lane loads one float4 (4 classes).
// Block of 256 threads processes 32 rows/iteration, reading a fully
// contiguous 4KB chunk from each input -> perfectly coalesced.
__global__ __launch_bounds__(256) void hist_kernel(
    const float* __restrict__ yt,
    const float* __restrict__ yp,
    unsigned int* __restrict__ ghist,
    int N)
{
    __shared__ unsigned int lhist[BINS];
    const int tid = threadIdx.x;
    for (int i = tid; i < BINS; i += blockDim.x) lhist[i] = 0u;
    __syncthreads();

    const int lane8 = tid & 7;        // which float4 within the row
    const int rowInBlock = tid >> 3;  // 0..31
    const int rowsPerIter = (gridDim.x * blockDim.x) >> 3;
    int row = blockIdx.x * (blockDim.x >> 3) + rowInBlock;

    for (; row < N; row += rowsPerIter) {
        const float4 a = ((const float4*)(yt + (size_t)row * C))[lane8];
        const float4 b = ((const float4*)(yp + (size_t)row * C))[lane8];

        // local argmax over this lane's 4 elements (strict > keeps first occurrence)
        const int base = lane8 * 4;
        float tv = a.x; int ti = base;
        if (a.y > tv) { tv = a.y; ti = base + 1; }
        if (a.z > tv) { tv = a.z; ti = base + 2; }
        if (a.w > tv) { tv = a.w; ti = base + 3; }
        float pv = b.x; int pi = base;
        if (b.y > pv) { pv = b.y; pi = base + 1; }
        if (b.z > pv) { pv = b.z; pi = base + 2; }
        if (b.w > pv) { pv = b.w; pi = base + 3; }

        // argmax reduce across the aligned 8-lane group; tie -> smaller index
        #pragma unroll
        for (int m = 1; m < 8; m <<= 1) {
            float otv = __shfl_xor(tv, m);
            int   oti = __shfl_xor(ti, m);
            if (otv > tv || (otv == tv && oti < ti)) { tv = otv; ti = oti; }
            float opv = __shfl_xor(pv, m);
            int   opi = __shfl_xor(pi, m);
            if (opv > pv || (opv == pv && opi < pi)) { pv = opv; pi = opi; }
        }

        if (lane8 == 0) {
            atomicAdd(&lhist[ti * C + pi], 1u);
        }
    }

    __syncthreads();
    for (int i = tid; i < BINS; i += blockDim.x) {
        unsigned int v = lhist[i];
        if (v) atomicAdd(&ghist[i], v);
    }
}

// One wave: lane j<32 owns class j (column sum + diagonal), then
// shuffle-sum over 32 lanes -> mean -> out.
__global__ __launch_bounds__(64) void finalize_kernel(
    const unsigned int* __restrict__ ghist,
    const float* __restrict__ cm_in,
    float* __restrict__ out)
{
    const int j = threadIdx.x;
    float prec = 0.0f;
    if (j < C) {
        float pp = 0.0f;
        #pragma unroll
        for (int i = 0; i < C; ++i) {
            pp += (float)ghist[i * C + j] + cm_in[i * C + j];
        }
        float tp = (float)ghist[j * C + j] + cm_in[j * C + j];
        prec = tp / (pp + FLT_EPS);
    }
    #pragma unroll
    for (int m = 1; m < 32; m <<= 1) {
        prec += __shfl_xor(prec, m);
    }
    if (j == 0) out[0] = prec / (float)C;
}

extern "C" void kernel_launch(void* const* d_in, const int* in_sizes, int n_in,
                              void* d_out, int out_size, void* d_ws, size_t ws_size,
                              hipStream_t stream)
{
    const float* yt = (const float*)d_in[0];
    const float* yp = (const float*)d_in[1];
    const float* cm = (const float*)d_in[2];
    float* out = (float*)d_out;
    const int N = in_sizes[0] / C;

    unsigned int* ghist = (unsigned int*)d_ws;
    // d_ws is poisoned to 0xAA before every launch -> zero the histogram.
    hipMemsetAsync(ghist, 0, BINS * sizeof(unsigned int), stream);

    hist_kernel<<<1024, 256, 0, stream>>>(yt, yp, ghist, N);
    finalize_kernel<<<1, 64, 0, stream>>>(ghist, cm, out);
}

// Round 3
// 480.514 us; speedup vs baseline: 1.0137x; 1.0137x over previous
//
#include <hip/hip_runtime.h>

#define C 32
#define BINS (C * C)
#define TILE_ROWS 256
#define ROWPAD 36   // floats per row in LDS: bank(word 36r+c) = (4r+c)%32 -> conflict-free patterns below
#define NBLOCKS 1024
#define FLT_EPS 1.1920928955078125e-07f

typedef float v4f __attribute__((ext_vector_type(4)));  // native vector for nontemporal builtins

// One row per thread, staged through LDS.
// Staging: 256 threads x float4 = 32 rows per round, 8 rounds = 256-row tile,
//   fully coalesced 1KB/wave global reads. LDS write banks: 4((r+m)%8) groups,
//   8 lanes/group = aggregate-BW-bound (no penalty).
// Argmax: thread t scans row t with rotated column order c=(j+t)&31;
//   read bank = (4t + c)%32 = (5t+j)%32, 5 odd -> 2 lanes/bank = free.
__global__ __launch_bounds__(256) void hist_kernel(
    const float* __restrict__ yt,
    const float* __restrict__ yp,
    unsigned int* __restrict__ partial,  // [NBLOCKS][64]: 32 colsums then 32 diags
    int N)
{
    __shared__ float buf[TILE_ROWS * ROWPAD];
    __shared__ unsigned int lhist[BINS];
    const int t = threadIdx.x;
    for (int i = t; i < BINS; i += 256) lhist[i] = 0u;

    const int numTiles = (N + TILE_ROWS - 1) / TILE_ROWS;
    int ti_reg = 0;

    for (int tile = blockIdx.x; tile < numTiles; tile += gridDim.x) {
        const size_t row0 = (size_t)tile * TILE_ROWS;
        const int rowsValid = min(TILE_ROWS, N - (int)row0);

        // ---- stage yt tile ----
        {
            const v4f* src = (const v4f*)(yt + row0 * C);
            #pragma unroll
            for (int q = 0; q < 8; ++q) {
                const int lin = q * 256 + t;        // float4 index in tile
                const int r = lin >> 3, m = lin & 7;
                if (r < rowsValid) {
                    v4f v = __builtin_nontemporal_load(src + lin);
                    *(v4f*)&buf[r * ROWPAD + m * 4] = v;
                }
            }
        }
        __syncthreads();
        if (t < rowsValid) {
            float bv = -__builtin_inff(); int bi = C;
            const float* rowp = &buf[t * ROWPAD];
            #pragma unroll
            for (int j = 0; j < C; ++j) {
                const int c = (j + t) & (C - 1);
                const float v = rowp[c];
                const bool better = (v > bv) || (v == bv && c < bi);
                bv = better ? v : bv;
                bi = better ? c : bi;
            }
            ti_reg = bi;
        }
        __syncthreads();

        // ---- stage yp tile ----
        {
            const v4f* src = (const v4f*)(yp + row0 * C);
            #pragma unroll
            for (int q = 0; q < 8; ++q) {
                const int lin = q * 256 + t;
                const int r = lin >> 3, m = lin & 7;
                if (r < rowsValid) {
                    v4f v = __builtin_nontemporal_load(src + lin);
                    *(v4f*)&buf[r * ROWPAD + m * 4] = v;
                }
            }
        }
        __syncthreads();
        if (t < rowsValid) {
            float bv = -__builtin_inff(); int bi = C;
            const float* rowp = &buf[t * ROWPAD];
            #pragma unroll
            for (int j = 0; j < C; ++j) {
                const int c = (j + t) & (C - 1);
                const float v = rowp[c];
                const bool better = (v > bv) || (v == bv && c < bi);
                bv = better ? v : bv;
                bi = better ? c : bi;
            }
            atomicAdd(&lhist[ti_reg * C + bi], 1u);
        }
        __syncthreads();
    }

    // ---- reduce block-local histogram to 32 colsums + 32 diags (no global atomics) ----
    if (t < C) {
        unsigned int cs = 0;
        #pragma unroll
        for (int i = 0; i < C; ++i) cs += lhist[i * C + t];  // bank t for all i, distinct across threads
        partial[(size_t)blockIdx.x * 64 + t] = cs;
        partial[(size_t)blockIdx.x * 64 + C + t] = lhist[t * C + t];
    }
}

// Single block: sum per-block partials (coalesced 256B per 64-lane wave-iter),
// then compute macro precision.
__global__ __launch_bounds__(1024) void finalize_kernel(
    const unsigned int* __restrict__ partial,
    const float* __restrict__ cm_in,
    float* __restrict__ out)
{
    __shared__ float sums[16][64];
    const int tid = threadIdx.x;
    const int col = tid & 63;
    const int kg = tid >> 6;   // 0..15

    unsigned int s = 0;
    #pragma unroll 8
    for (int k = kg * (NBLOCKS / 16); k < (kg + 1) * (NBLOCKS / 16); ++k)
        s += partial[(size_t)k * 64 + col];
    sums[kg][col] = (float)s;
    __syncthreads();

    if (tid < 64) {
        float tot = 0.0f;
        #pragma unroll
        for (int g = 0; g < 16; ++g) tot += sums[g][tid];
        sums[0][tid] = tot;
    }
    __syncthreads();

    if (tid < C) {
        const int j = tid;
        float pp = sums[0][j];       // histogram column sum for class j
        float tp = sums[0][C + j];   // histogram diagonal for class j
        float cmcol = 0.0f;
        #pragma unroll
        for (int i = 0; i < C; ++i) cmcol += cm_in[i * C + j];
        pp += cmcol;
        tp += cm_in[j * C + j];
        float prec = tp / (pp + FLT_EPS);
        #pragma unroll
        for (int m = 1; m < C; m <<= 1) prec += __shfl_xor(prec, m);
        if (j == 0) out[0] = prec * (1.0f / (float)C);
    }
}

extern "C" void kernel_launch(void* const* d_in, const int* in_sizes, int n_in,
                              void* d_out, int out_size, void* d_ws, size_t ws_size,
                              hipStream_t stream)
{
    const float* yt = (const float*)d_in[0];
    const float* yp = (const float*)d_in[1];
    const float* cm = (const float*)d_in[2];
    float* out = (float*)d_out;
    const int N = in_sizes[0] / C;

    unsigned int* partial = (unsigned int*)d_ws;  // NBLOCKS*64 u32 = 256 KB, fully overwritten each call

    hist_kernel<<<NBLOCKS, 256, 0, stream>>>(yt, yp, partial, N);
    finalize_kernel<<<1, 1024, 0, stream>>>(partial, cm, out);
}

// Round 4
// 461.293 us; speedup vs baseline: 1.0559x; 1.0417x over previous
//
#include <hip/hip_runtime.h>

#define C 32
#define BINS (C * C)
#define NBLOCKS 2048
#define NTHREADS 256
#define ROWS_PER_STEP ((NBLOCKS * NTHREADS) / 8)   // 65536 rows per grid stride
#define FLT_EPS 1.1920928955078125e-07f

typedef float v4f __attribute__((ext_vector_type(4)));

// Monotone float->u32 key, packed with (63-idx) so that u64 max == argmax with
// first-occurrence tie-break (larger 63-idx == smaller idx).
__device__ __forceinline__ unsigned long long pack_best4(v4f v, int base) {
    unsigned long long best = 0ull;
    #pragma unroll
    for (int k = 0; k < 4; ++k) {
        unsigned int u = __float_as_uint(v[k]);
        unsigned int key = u ^ ((unsigned int)((int)u >> 31) | 0x80000000u);
        unsigned long long p =
            ((unsigned long long)key << 32) | (unsigned int)(63 - (base + k));
        best = (p > best) ? p : best;
    }
    return best;
}

// 8 lanes per row, float4 each -> every load instr is a contiguous 1KB wave
// transaction. Barrier-free hot loop with next-iteration prefetch (4 loads in
// flight per wave); 2048 blocks = 32 waves/CU for memory-level parallelism.
__global__ __launch_bounds__(NTHREADS) void hist_kernel(
    const float* __restrict__ yt,
    const float* __restrict__ yp,
    unsigned int* __restrict__ partial,  // [NBLOCKS][64]: 32 colsums, 32 diags
    int N)
{
    __shared__ unsigned int lhist[BINS];
    const int t = threadIdx.x;
    for (int i = t; i < BINS; i += NTHREADS) lhist[i] = 0u;
    __syncthreads();

    const int lane8 = t & 7;
    long long row = (long long)((blockIdx.x * NTHREADS + t) >> 3);
    bool valid = row < N;
    v4f a, b;
    if (valid) {
        a = __builtin_nontemporal_load(((const v4f*)(yt + row * C)) + lane8);
        b = __builtin_nontemporal_load(((const v4f*)(yp + row * C)) + lane8);
    }

    while (valid) {  // validity is uniform within each 8-lane group -> shuffles safe
        const long long nrow = row + ROWS_PER_STEP;
        const bool nvalid = nrow < N;
        v4f na, nb;
        if (nvalid) {  // prefetch next iteration while we reduce this one
            na = __builtin_nontemporal_load(((const v4f*)(yt + nrow * C)) + lane8);
            nb = __builtin_nontemporal_load(((const v4f*)(yp + nrow * C)) + lane8);
        }

        unsigned long long bt = pack_best4(a, lane8 * 4);
        unsigned long long bp = pack_best4(b, lane8 * 4);
        #pragma unroll
        for (int m = 1; m < 8; m <<= 1) {
            unsigned long long ot = __shfl_xor(bt, m);
            bt = (ot > bt) ? ot : bt;
            unsigned long long op = __shfl_xor(bp, m);
            bp = (op > bp) ? op : bp;
        }
        if (lane8 == 0) {
            const int ti = 63 - (int)(bt & 63ull);
            const int pi = 63 - (int)(bp & 63ull);
            atomicAdd(&lhist[ti * C + pi], 1u);
        }

        row = nrow; valid = nvalid; a = na; b = nb;
    }

    __syncthreads();
    if (t < 32) {
        unsigned int cs = 0;
        #pragma unroll
        for (int i = 0; i < C; ++i) cs += lhist[i * C + t];  // bank t for all i
        partial[(size_t)blockIdx.x * 64 + t] = cs;
    } else if (t < 64) {
        const int j = t - 32;
        partial[(size_t)blockIdx.x * 64 + t] = lhist[j * C + j];
    }
}

// Single block: sum [NBLOCKS][64] partials (coalesced), compute macro precision.
__global__ __launch_bounds__(1024) void finalize_kernel(
    const unsigned int* __restrict__ partial,
    const float* __restrict__ cm_in,
    float* __restrict__ out)
{
    __shared__ float sums[16][64];
    const int tid = threadIdx.x;
    const int col = tid & 63;
    const int kg = tid >> 6;   // 0..15

    unsigned int s = 0;
    #pragma unroll 8
    for (int k = kg * (NBLOCKS / 16); k < (kg + 1) * (NBLOCKS / 16); ++k)
        s += partial[(size_t)k * 64 + col];
    sums[kg][col] = (float)s;
    __syncthreads();

    if (tid < 64) {
        float tot = 0.0f;
        #pragma unroll
        for (int g = 0; g < 16; ++g) tot += sums[g][tid];
        sums[0][tid] = tot;
    }
    __syncthreads();

    if (tid < C) {
        const int j = tid;
        float pp = sums[0][j];       // histogram column sum for class j
        float tp = sums[0][C + j];   // histogram diagonal for class j
        float cmcol = 0.0f;
        #pragma unroll
        for (int i = 0; i < C; ++i) cmcol += cm_in[i * C + j];
        pp += cmcol;
        tp += cm_in[j * C + j];
        float prec = tp / (pp + FLT_EPS);
        #pragma unroll
        for (int m = 1; m < C; m <<= 1) prec += __shfl_xor(prec, m);
        if (j == 0) out[0] = prec * (1.0f / (float)C);
    }
}

extern "C" void kernel_launch(void* const* d_in, const int* in_sizes, int n_in,
                              void* d_out, int out_size, void* d_ws, size_t ws_size,
                              hipStream_t stream)
{
    const float* yt = (const float*)d_in[0];
    const float* yp = (const float*)d_in[1];
    const float* cm = (const float*)d_in[2];
    float* out = (float*)d_out;
    const int N = in_sizes[0] / C;

    unsigned int* partial = (unsigned int*)d_ws;  // NBLOCKS*64 u32 = 512 KB, fully overwritten

    hist_kernel<<<NBLOCKS, NTHREADS, 0, stream>>>(yt, yp, partial, N);
    finalize_kernel<<<1, 1024, 0, stream>>>(partial, cm, out);
}